// Round 1
// baseline (4576.896 us; speedup 1.0000x reference)
//
#include <hip/hip_runtime.h>

// GRU persistent-scan kernel for MI355X (gfx950). Round 6.
// B=128, T=512, I=256, H=512. Global I/O f32; GEMMs bf16 MFMA, f32 accum.
//
// Structure change vs round 5: latency-bound on 2 cross-WG hops/step
// (flag RT + serial gather RT + 3 __syncthreads = ~7.6us/step of stall).
// Now: 256 blocks x 64 threads (8 clusters x 32 independent waves, 16 cols
// each). NO barriers. NO flags. Consumers poll the payload itself:
//  - h / r*h exchanged as u64-packed bf16 words in a 2-slot ping-pong,
//    slots pre-memset to SENTINEL (~0 = 4x bf16 NaN, unreachable from
//    finite values through f2b).
//  - detection == gather: fragments load straight into MFMA A-frag regs.
//  - writer-self-reset gives freshness: reset of h(t)'s slot happens only
//    after rh(t) poll completes (=> every wave consumed h(t)); reset of
//    rh(t-1)'s slot after h(t) poll completes. One s_waitcnt(0) before the
//    h-publish orders both resets ahead of the publish that gates any
//    future reader of those slots (same drain->store visibility property
//    round 5's flag protocol relied on).
// LDS reduced to a 512B wave-local repack tile (no bank conflicts).

typedef __attribute__((ext_vector_type(8))) short bf16x8;
typedef __attribute__((ext_vector_type(4))) float f32x4;
typedef unsigned short u16;
typedef unsigned int u32;
typedef unsigned long long u64;

#define B_ 128
#define T_ 512
#define I_ 256
#define H_ 512
#define SLOT_ 16384                      // u64 words per [B,H] bf16 slot
#define SENT_ 0xFFFFFFFFFFFFFFFFull      // 4x bf16 -NaN: unreachable payload

__device__ __forceinline__ u16 f2b(float f) {
  union { float f; u32 i; } v; v.f = f;
  u32 u = v.i;
  return (u16)((u + 0x7FFFu + ((u >> 16) & 1u)) >> 16);  // RNE
}

__device__ __forceinline__ u64 aload(u64* p) {
  return __hip_atomic_load(p, __ATOMIC_RELAXED, __HIP_MEMORY_SCOPE_AGENT);
}
__device__ __forceinline__ void astore(u64* p, u64 v) {
  __hip_atomic_store(p, v, __ATOMIC_RELAXED, __HIP_MEMORY_SCOPE_AGENT);
}

// prep: convert 6 weight tensors f32 -> bf16 into ws
// layout: Rz[512x512], Rr, Rh, Wz[512x256], Wr, Wh; row-major [out][in]
__global__ void prep_weights(const float* __restrict__ rz, const float* __restrict__ rr,
                             const float* __restrict__ rh, const float* __restrict__ wz,
                             const float* __restrict__ wr, const float* __restrict__ wh,
                             u16* __restrict__ wout) {
  int idx = blockIdx.x * 256 + threadIdx.x;
  if (idx >= 1179648) return;
  float v;
  if (idx < 262144)       v = rz[idx];
  else if (idx < 524288)  v = rr[idx - 262144];
  else if (idx < 786432)  v = rh[idx - 524288];
  else if (idx < 917504)  v = wz[idx - 786432];
  else if (idx < 1048576) v = wr[idx - 917504];
  else                    v = wh[idx - 1048576];
  wout[idx] = f2b(v);
}

__global__ __launch_bounds__(64, 1) void gru_persist(
    const float* __restrict__ x, const float* __restrict__ h0,
    const u16* __restrict__ wsW,
    const float* __restrict__ bwz, const float* __restrict__ bwr, const float* __restrict__ bwh,
    const float* __restrict__ brz, const float* __restrict__ brr, const float* __restrict__ brh,
    float* __restrict__ out, u64* __restrict__ hb, u64* __restrict__ rhb)
{
  const int lane = threadIdx.x;     // 0..63, one wave per block
  const int n    = lane & 15;       // MFMA A-row m == B-col n == C col
  const int q    = lane >> 4;       // quad; k-chunk q*8; C rows 4q..4q+3
  const int c    = blockIdx.x >> 5; // cluster 0..7 (16 batch rows)
  const int sl   = blockIdx.x & 31; // col-slice 0..31 (16 H cols)
  const int nj   = sl * 16 + n;     // global H column of this lane
  const int b0   = c * 16;          // batch base row

  const u16* wrz = wsW;             // [512][512]
  const u16* wrr = wsW + 262144;
  const u16* wrh = wsW + 524288;
  const u16* wwz = wsW + 786432;    // [512][256]
  const u16* wwr = wsW + 917504;
  const u16* wwh = wsW + 1048576;

  // ---- preload ALL weight fragments for this lane's column into registers
  bf16x8 rzf[16], rrf[16], rhf[16], wzf[8], wrf[8], whf[8];
#pragma unroll
  for (int kb = 0; kb < 16; ++kb) {
    rzf[kb] = *(const bf16x8*)&wrz[nj * H_ + kb * 32 + q * 8];
    rrf[kb] = *(const bf16x8*)&wrr[nj * H_ + kb * 32 + q * 8];
    rhf[kb] = *(const bf16x8*)&wrh[nj * H_ + kb * 32 + q * 8];
  }
#pragma unroll
  for (int kb = 0; kb < 8; ++kb) {
    wzf[kb] = *(const bf16x8*)&wwz[nj * I_ + kb * 32 + q * 8];
    wrf[kb] = *(const bf16x8*)&wwr[nj * I_ + kb * 32 + q * 8];
    whf[kb] = *(const bf16x8*)&wwh[nj * I_ + kb * 32 + q * 8];
  }

  const float bz  = bwz[nj] + brz[nj];
  const float brg = bwr[nj] + brr[nj];
  const float bhg = bwh[nj] + brh[nj];

  float hold[4];
#pragma unroll
  for (int i = 0; i < 4; ++i) hold[i] = h0[(b0 + q * 4 + i) * H_ + nj];

  __shared__ __align__(8) u16 sT[256];   // wave-local publish repack (512 B)

  // publish-lane geometry: lane l stores u64 = 4 cols of one row of the tile
  const int prow = lane >> 2, pcq = lane & 3;
  const int pubidx = ((b0 + prow) * H_ + sl * 16 + pcq * 4) >> 2;
  // gather geometry: frag kb = 16B at row (b0+n), halves kb*32+q*8
  const int gb = ((b0 + n) * H_) >> 2;

  // ---- initial publish of h(0) into slot 0 (slots pre-memset to SENT_)
#pragma unroll
  for (int i = 0; i < 4; ++i) sT[(q * 4 + i) * 16 + n] = f2b(hold[i]);
  __threadfence_block();
  astore(&hb[pubidx], *(const u64*)&sT[prow * 16 + pcq * 4]);

  for (int t = 0; t < T_; ++t) {
    const int so = (t & 1) * SLOT_;
    const int sn = SLOT_ - so;
    u64* hbC = hb + so;     // holds h(t)
    u64* hbN = hb + sn;     // dest for h(t+1)
    u64* rhC = rhb + so;    // dest/source for rh(t)
    u64* rhP = rhb + sn;    // old rh slot to reset (readers provably done)

    // ---- issue h(t) gather early (straight into frag words)
    u64 w0[16], w1[16];
#pragma unroll
    for (int kb = 0; kb < 16; ++kb) {
      w0[kb] = aload(&hbC[gb + kb * 8 + q * 2]);
      w1[kb] = aload(&hbC[gb + kb * 8 + q * 2 + 1]);
    }

    // ---- x_t load/convert + ALL x-side MFMAs (independent of h; hides hop)
    bf16x8 xf[8];
    const float* xrow = &x[(b0 + n) * (T_ * I_) + t * I_ + q * 8];
#pragma unroll
    for (int kb = 0; kb < 8; ++kb) {
      float4 v0 = *(const float4*)(xrow + kb * 32);
      float4 v1 = *(const float4*)(xrow + kb * 32 + 4);
      union { u16 u[8]; bf16x8 v; } pk;
      pk.u[0] = f2b(v0.x); pk.u[1] = f2b(v0.y); pk.u[2] = f2b(v0.z); pk.u[3] = f2b(v0.w);
      pk.u[4] = f2b(v1.x); pk.u[5] = f2b(v1.y); pk.u[6] = f2b(v1.z); pk.u[7] = f2b(v1.w);
      xf[kb] = pk.v;
    }
    f32x4 az0 = {0.f, 0.f, 0.f, 0.f};
    f32x4 az1 = az0, ar0 = az0, ar1 = az0, ah0 = az0, ah1 = az0;
#pragma unroll
    for (int kb = 0; kb < 8; kb += 2) {
      az0 = __builtin_amdgcn_mfma_f32_16x16x32_bf16(xf[kb], wzf[kb], az0, 0, 0, 0);
      ar0 = __builtin_amdgcn_mfma_f32_16x16x32_bf16(xf[kb], wrf[kb], ar0, 0, 0, 0);
      ah0 = __builtin_amdgcn_mfma_f32_16x16x32_bf16(xf[kb], whf[kb], ah0, 0, 0, 0);
      az1 = __builtin_amdgcn_mfma_f32_16x16x32_bf16(xf[kb + 1], wzf[kb + 1], az1, 0, 0, 0);
      ar1 = __builtin_amdgcn_mfma_f32_16x16x32_bf16(xf[kb + 1], wrf[kb + 1], ar1, 0, 0, 0);
      ah1 = __builtin_amdgcn_mfma_f32_16x16x32_bf16(xf[kb + 1], whf[kb + 1], ah1, 0, 0, 0);
    }

    // ---- poll h(t): detection == gather; reload only sentinel words
    for (;;) {
      bool ok = true;
#pragma unroll
      for (int kb = 0; kb < 16; ++kb)
        ok = ok & (w0[kb] != SENT_) & (w1[kb] != SENT_);
      if (__ballot(ok) == ~0ull) break;
#pragma unroll
      for (int kb = 0; kb < 16; ++kb) {
        if (w0[kb] == SENT_) w0[kb] = aload(&hbC[gb + kb * 8 + q * 2]);
        if (w1[kb] == SENT_) w1[kb] = aload(&hbC[gb + kb * 8 + q * 2 + 1]);
      }
    }

    // h(t) complete => every wave published rh(t-1)&consumed rh(t-1) slot:
    // reset our word of the old rh slot (becomes rh(t+1)'s sentinel).
    astore(&rhP[pubidx], SENT_);

    // ---- z/r recurrent MFMAs (frags straight from gathered words)
#pragma unroll
    for (int kb = 0; kb < 16; kb += 2) {
      union { u64 qd[2]; bf16x8 v; } a0, a1;
      a0.qd[0] = w0[kb];     a0.qd[1] = w1[kb];
      a1.qd[0] = w0[kb + 1]; a1.qd[1] = w1[kb + 1];
      az0 = __builtin_amdgcn_mfma_f32_16x16x32_bf16(a0.v, rzf[kb], az0, 0, 0, 0);
      ar0 = __builtin_amdgcn_mfma_f32_16x16x32_bf16(a0.v, rrf[kb], ar0, 0, 0, 0);
      az1 = __builtin_amdgcn_mfma_f32_16x16x32_bf16(a1.v, rzf[kb + 1], az1, 0, 0, 0);
      ar1 = __builtin_amdgcn_mfma_f32_16x16x32_bf16(a1.v, rrf[kb + 1], ar1, 0, 0, 0);
    }

    // ---- gates; publish rh(t) (self-announcing, no drain needed)
    float zreg[4];
#pragma unroll
    for (int i = 0; i < 4; ++i) {
      zreg[i] = 1.f / (1.f + __expf(-(az0[i] + az1[i] + bz)));
      float rv = 1.f / (1.f + __expf(-(ar0[i] + ar1[i] + brg)));
      sT[(q * 4 + i) * 16 + n] = f2b(rv * hold[i]);
    }
    __threadfence_block();
    astore(&rhC[pubidx], *(const u64*)&sT[prow * 16 + pcq * 4]);

    // ---- gather + poll rh(t)
#pragma unroll
    for (int kb = 0; kb < 16; ++kb) {
      w0[kb] = aload(&rhC[gb + kb * 8 + q * 2]);
      w1[kb] = aload(&rhC[gb + kb * 8 + q * 2 + 1]);
    }
    for (;;) {
      bool ok = true;
#pragma unroll
      for (int kb = 0; kb < 16; ++kb)
        ok = ok & (w0[kb] != SENT_) & (w1[kb] != SENT_);
      if (__ballot(ok) == ~0ull) break;
#pragma unroll
      for (int kb = 0; kb < 16; ++kb) {
        if (w0[kb] == SENT_) w0[kb] = aload(&rhC[gb + kb * 8 + q * 2]);
        if (w1[kb] == SENT_) w1[kb] = aload(&rhC[gb + kb * 8 + q * 2 + 1]);
      }
    }

    // rh(t) complete => every wave consumed h(t): reset our h(t) word
    // (slot becomes h(t+2)'s sentinel).
    astore(&hbC[pubidx], SENT_);

    // ---- hh recurrent MFMAs
#pragma unroll
    for (int kb = 0; kb < 16; kb += 2) {
      union { u64 qd[2]; bf16x8 v; } a0, a1;
      a0.qd[0] = w0[kb];     a0.qd[1] = w1[kb];
      a1.qd[0] = w0[kb + 1]; a1.qd[1] = w1[kb + 1];
      ah0 = __builtin_amdgcn_mfma_f32_16x16x32_bf16(a0.v, rhf[kb], ah0, 0, 0, 0);
      ah1 = __builtin_amdgcn_mfma_f32_16x16x32_bf16(a1.v, rhf[kb + 1], ah1, 0, 0, 0);
    }

    // ---- epilogue: h' = (1-z)*tanh(.) + z*h ; drain (orders this step's
    // two resets ahead of the publish) ; publish h(t+1)
#pragma unroll
    for (int i = 0; i < 4; ++i) {
      float hhv = tanhf(ah0[i] + ah1[i] + bhg);
      float hn  = (1.f - zreg[i]) * hhv + zreg[i] * hold[i];
      hold[i] = hn;
      sT[(q * 4 + i) * 16 + n] = f2b(hn);
    }
    __threadfence_block();
    __builtin_amdgcn_s_waitcnt(0);
    astore(&hbN[pubidx], *(const u64*)&sT[prow * 16 + pcq * 4]);

    // ---- out stores AFTER the publish (fire-and-forget, off critical path)
#pragma unroll
    for (int i = 0; i < 4; ++i) {
      out[(b0 + q * 4 + i) * (T_ * H_) + t * H_ + nj] = hold[i];
      if (t == T_ - 1) out[B_ * T_ * H_ + (b0 + q * 4 + i) * H_ + nj] = hold[i];
    }
  }
}

extern "C" void kernel_launch(void* const* d_in, const int* in_sizes, int n_in,
                              void* d_out, int out_size, void* d_ws, size_t ws_size,
                              hipStream_t stream) {
  const float* xp   = (const float*)d_in[0];
  const float* h0p  = (const float*)d_in[1];
  const float* wzp  = (const float*)d_in[2];
  const float* wrp  = (const float*)d_in[3];
  const float* whp  = (const float*)d_in[4];
  const float* rzp  = (const float*)d_in[5];
  const float* rrp  = (const float*)d_in[6];
  const float* rhp  = (const float*)d_in[7];
  const float* bwzp = (const float*)d_in[8];
  const float* bwrp = (const float*)d_in[9];
  const float* bwhp = (const float*)d_in[10];
  const float* brzp = (const float*)d_in[11];
  const float* brrp = (const float*)d_in[12];
  const float* brhp = (const float*)d_in[13];

  unsigned char* ws = (unsigned char*)d_ws;
  u16* wsW = (u16*)(ws);             // 1,179,648 bf16 weights (2,359,296 B)
  u64* hb  = (u64*)(ws + 2359296);   // 2 ping-pong slots of [B,H] bf16 h
  u64* rhb = (u64*)(ws + 2621440);   // 2 ping-pong slots of [B,H] bf16 r*h

  // all 4 exchange slots start as sentinel
  hipMemsetAsync(ws + 2359296, 0xFF, 524288, stream);

  prep_weights<<<dim3(4608), dim3(256), 0, stream>>>(rzp, rrp, rhp, wzp, wrp, whp, wsW);

  gru_persist<<<dim3(256), dim3(64), 0, stream>>>(
      xp, h0p, wsW,
      bwzp, bwrp, bwhp, brzp, brrp, brhp,
      (float*)d_out, hb, rhb);
}